// Round 4
// baseline (379.149 us; speedup 1.0000x reference)
//
#include <hip/hip_runtime.h>
#include <cstddef>

#define NS 64000
#define GROUP 8000
#define TM 32

typedef __bf16 bf16x8 __attribute__((ext_vector_type(8)));
typedef float floatx4 __attribute__((ext_vector_type(4)));
typedef unsigned short ushort_t;

// ---------------- ws layout (bytes): only mixed weights ----------------
static const size_t BY_W0 = 0;                      // 8*192*192*2 = 589824
static const size_t BY_W1 = BY_W0 + 589824;         // 8*256*256*2 = 1048576
static const size_t BY_W2 = BY_W1 + 1048576;        // 8*128*128*2 = 262144
static const size_t BY_B0 = BY_W2 + 262144;         // 8*192*4     = 6144

__device__ __forceinline__ unsigned short f2bf(float f) {
    unsigned u = __float_as_uint(f);
    u += 0x7fff + ((u >> 16) & 1);   // RNE
    return (unsigned short)(u >> 16);
}

// ---------------- expert-mix kernel (bf16 weights out) ----------------
__global__ __launch_bounds__(256) void mix_kernel(
    const float* __restrict__ coef,
    const float* __restrict__ w_m0, const float* __restrict__ b_m0,
    const float* __restrict__ ws_m0, const float* __restrict__ bs_m0,
    const float* __restrict__ w_m1, const float* __restrict__ ws_m1,
    const float* __restrict__ w_m2, const float* __restrict__ ws_m2,
    ushort_t* __restrict__ W0, float* __restrict__ B0,
    ushort_t* __restrict__ W1, ushort_t* __restrict__ W2)
{
    int tid = blockIdx.x * 256 + threadIdx.x;
    if (tid < 294912) {
        int b = tid / 36864, rem = tid % 36864;
        float s = ws_m0[rem];
        #pragma unroll
        for (int e = 0; e < 8; e++) s += coef[b * 8 + e] * w_m0[e * 36864 + rem];
        W0[tid] = f2bf(s);
    } else if (tid < 296448) {
        int i2 = tid - 294912;
        int b = i2 / 192, o = i2 % 192;
        float s = bs_m0[o];
        #pragma unroll
        for (int e = 0; e < 8; e++) s += coef[b * 8 + e] * b_m0[e * 192 + o];
        B0[i2] = s;
    } else if (tid < 820736) {
        // W1big[b,o,i] (256x256): [[Wr,-Wi],[Wi,Wr]] fold of mixed 256x128 w_m1
        int i3 = tid - 296448;
        int b = i3 >> 16, rem = i3 & 65535;
        int o = rem >> 8, i = rem & 255;
        int r, cc; float sign = 1.0f;
        if (o < 128) { if (i < 128) { r = o;       cc = i; } else { r = 128 + o;      cc = i - 128; sign = -1.0f; } }
        else { int o2 = o - 128; if (i < 128) { r = 128 + o2; cc = i; } else { r = o2; cc = i - 128; } }
        int idx = r * 128 + cc;
        float s = ws_m1[idx];
        #pragma unroll
        for (int e = 0; e < 8; e++) s += coef[b * 8 + e] * w_m1[e * 32768 + idx];
        W1[i3] = f2bf(sign * s);
    } else if (tid < 951808) {
        int i4 = tid - 820736;
        int b = i4 >> 14, rem = i4 & 16383;
        int o = rem >> 7, i = rem & 127;
        int r, cc; float sign = 1.0f;
        if (o < 64) { if (i < 64) { r = o;      cc = i; } else { r = 64 + o;      cc = i - 64; sign = -1.0f; } }
        else { int o2 = o - 64; if (i < 64) { r = 64 + o2; cc = i; } else { r = o2; cc = i - 64; } }
        int idx = r * 64 + cc;
        float s = ws_m2[idx];
        #pragma unroll
        for (int e = 0; e < 8; e++) s += coef[b * 8 + e] * w_m2[e * 8192 + idx];
        W2[i4] = f2bf(sign * s);
    }
}

// ---------------- rotation helpers ----------------
__device__ __forceinline__ void zrot1(float& v0, float& v2, float c, float s) {
    float t0 = c * v0 + s * v2;
    v2 = -s * v0 + c * v2;
    v0 = t0;
}
__device__ __forceinline__ void j1mul(const float* J, float& v0, float& v1, float& v2) {
    float w0 = J[0] * v0 + J[1] * v1 + J[2] * v2;
    float w1 = J[3] * v0 + J[4] * v1 + J[5] * v2;
    float w2 = J[6] * v0 + J[7] * v1 + J[8] * v2;
    v0 = w0; v1 = w1; v2 = w2;
}
__device__ __forceinline__ void zrot2(float& u0, float& u1, float& u3, float& u4,
                                      float c1, float s1, float c2, float s2) {
    float t0 = c2 * u0 + s2 * u4;
    u4 = -s2 * u0 + c2 * u4;
    u0 = t0;
    float t1 = c1 * u1 + s1 * u3;
    u3 = -s1 * u1 + c1 * u3;
    u1 = t1;
}
__device__ __forceinline__ void j2mul(const float* J, float& u0, float& u1, float& u2, float& u3, float& u4) {
    float w0 = J[0]  * u0 + J[1]  * u1 + J[2]  * u2 + J[3]  * u3 + J[4]  * u4;
    float w1 = J[5]  * u0 + J[6]  * u1 + J[7]  * u2 + J[8]  * u3 + J[9]  * u4;
    float w2 = J[10] * u0 + J[11] * u1 + J[12] * u2 + J[13] * u3 + J[14] * u4;
    float w3 = J[15] * u0 + J[16] * u1 + J[17] * u2 + J[18] * u3 + J[19] * u4;
    float w4 = J[20] * u0 + J[21] * u1 + J[22] * u2 + J[23] * u3 + J[24] * u4;
    u0 = w0; u1 = w1; u2 = w2; u3 = w3; u4 = w4;
}

// swizzled LDS element index: row-major [row][K], 16B granules XOR'd by row&7.
__device__ __forceinline__ int sidx(int row, int k, int K) {
    int gr = (k >> 3) ^ (row & 7);
    return row * K + gr * 8 + (k & 7);
}
__device__ __forceinline__ float yread(const ushort_t* L, int row, int k, int K) {
    unsigned u = L[sidx(row, k, K)];
    return __uint_as_float(u << 16);
}

// ---------------- per-wave GEMM segment (M=32): acc[t][ms] += X(LDS) * Wseg ----------------
template<int K, int NT>
__device__ __forceinline__ void gemm_seg(
    floatx4 (*acc)[2],
    const ushort_t* __restrict__ Wseg,   // global (L2-resident), row-major K-length rows
    const ushort_t* XL_,                 // LDS region, swizzled
    int mi, int quad)
{
    #pragma unroll
    for (int k0 = 0; k0 < K; k0 += 32) {
        bf16x8 af[2];
        #pragma unroll
        for (int ms = 0; ms < 2; ms++) {
            int row = ms * 16 + mi;
            int gr = ((k0 >> 3) + quad) ^ (row & 7);
            af[ms] = *(const bf16x8*)&XL_[row * K + gr * 8];
        }
        bf16x8 bfr[NT];
        #pragma unroll
        for (int t = 0; t < NT; t++)
            bfr[t] = *(const bf16x8*)&Wseg[(size_t)(t * 16 + mi) * K + k0 + quad * 8];
        #pragma unroll
        for (int t = 0; t < NT; t++)
            #pragma unroll
            for (int ms = 0; ms < 2; ms++)
                acc[t][ms] = __builtin_amdgcn_mfma_f32_16x16x32_bf16(af[ms], bfr[t], acc[t][ms], 0, 0, 0);
    }
}

// write acc tiles into LDS Y (bf16, same swizzled layout), optional bias
template<int K, int NT, bool BIAS>
__device__ __forceinline__ void ywrite(
    floatx4 (*acc)[2], ushort_t* L, int n0, const float* __restrict__ bias,
    int mi, int quad)
{
    #pragma unroll
    for (int t = 0; t < NT; t++) {
        int col = n0 + t * 16 + mi;
        float bv = BIAS ? bias[col] : 0.f;
        int gc = col >> 3, kw = col & 7;
        #pragma unroll
        for (int ms = 0; ms < 2; ms++) {
            #pragma unroll
            for (int r = 0; r < 4; r++) {
                int m = ms * 16 + quad * 4 + r;
                L[m * K + ((gc ^ (m & 7)) * 8) + kw] = f2bf(acc[t][ms][r] + bv);
            }
        }
    }
}

// ---------------- fused: rotate -> 3 GEMMs -> inverse rotate ----------------
__global__ __launch_bounds__(256, 3) void fused_kernel(
    const float* __restrict__ x,
    const float* __restrict__ alpha, const float* __restrict__ beta, const float* __restrict__ gamma_,
    const float* __restrict__ Jd1, const float* __restrict__ Jd2,
    const ushort_t* __restrict__ W0, const ushort_t* __restrict__ W1, const ushort_t* __restrict__ W2,
    const float* __restrict__ B0,
    float* __restrict__ out)
{
    __shared__ ushort_t XL[18432];   // X0(32x192) | X1(32x256) | X2(32x128), bf16 swizzled
    __shared__ float TR[TM * 6];
    __shared__ float JL[34];

    ushort_t* X0L = XL;
    ushort_t* X1L = XL + 6144;
    ushort_t* X2L = XL + 14336;

    int t = threadIdx.x;
    int w = t >> 6, lane = t & 63;
    int g = blockIdx.x / 250;
    int base = g * GROUP + (blockIdx.x % 250) * TM;

    if (t < TM) {
        int n = base + t;
        float sa, ca, sb, cb, sg, cg;
        __sincosf(alpha[n],  &sa, &ca);
        __sincosf(beta[n],   &sb, &cb);
        __sincosf(gamma_[n], &sg, &cg);
        TR[t * 6 + 0] = sa; TR[t * 6 + 1] = ca;
        TR[t * 6 + 2] = sb; TR[t * 6 + 3] = cb;
        TR[t * 6 + 4] = sg; TR[t * 6 + 5] = cg;
    } else if (t < TM + 34) {
        int j = t - TM;
        JL[j] = (j < 9) ? Jd1[j] : Jd2[j - 9];
    }
    __syncthreads();

    const float* J1 = JL;
    const float* J2 = JL + 9;
    int c = lane;

    // ---- phase A: forward rotate x -> LDS bf16 (8 rows/thread, fully unrolled) ----
    #pragma unroll
    for (int i = 0; i < 8; i++) {
        int nl = w * 8 + i;
        const float* xr = x + (size_t)(base + nl) * 576;
        float x0 = xr[c];
        float v0 = xr[64 + 3 * c], v1 = xr[64 + 3 * c + 1], v2 = xr[64 + 3 * c + 2];
        float u0 = xr[256 + 5 * c], u1 = xr[256 + 5 * c + 1], u2 = xr[256 + 5 * c + 2],
              u3 = xr[256 + 5 * c + 3], u4 = xr[256 + 5 * c + 4];

        float sa = TR[nl * 6 + 0], ca = TR[nl * 6 + 1];
        float sb = TR[nl * 6 + 2], cb = TR[nl * 6 + 3];
        float sg = TR[nl * 6 + 4], cg = TR[nl * 6 + 5];
        float s2a = 2.f * sa * ca, c2a = ca * ca - sa * sa;
        float s2b = 2.f * sb * cb, c2b = cb * cb - sb * sb;
        float s2g = 2.f * sg * cg, c2g = cg * cg - sg * sg;

        zrot1(v0, v2, cg, sg);
        j1mul(J1, v0, v1, v2);
        zrot1(v0, v2, cb, sb);
        j1mul(J1, v0, v1, v2);
        zrot1(v0, v2, ca, sa);

        zrot2(u0, u1, u3, u4, cg, sg, c2g, s2g);
        j2mul(J2, u0, u1, u2, u3, u4);
        zrot2(u0, u1, u3, u4, cb, sb, c2b, s2b);
        j2mul(J2, u0, u1, u2, u3, u4);
        zrot2(u0, u1, u3, u4, ca, sa, c2a, s2a);

        X0L[sidx(nl, c, 192)]       = f2bf(x0);
        X0L[sidx(nl, 64 + c, 192)]  = f2bf(v1);
        X0L[sidx(nl, 128 + c, 192)] = f2bf(u2);
        X1L[sidx(nl, c, 256)]       = f2bf(v0);
        X1L[sidx(nl, 64 + c, 256)]  = f2bf(u1);
        X1L[sidx(nl, 128 + c, 256)] = f2bf(v2);
        X1L[sidx(nl, 192 + c, 256)] = f2bf(u3);
        X2L[sidx(nl, c, 128)]       = f2bf(u0);
        X2L[sidx(nl, 64 + c, 128)]  = f2bf(u4);
    }
    __syncthreads();

    // ---- phase B: MFMA GEMMs, B-fragments streamed from L2 ----
    int mi = lane & 15, quad = lane >> 4;
    floatx4 acc[10][2];
    #pragma unroll
    for (int a = 0; a < 10; a++)
        #pragma unroll
        for (int b2 = 0; b2 < 2; b2++) acc[a][b2] = (floatx4)0.f;

    const ushort_t* W0g = W0 + (size_t)g * 192 * 192;
    const ushort_t* W1g = W1 + (size_t)g * 256 * 256;
    const ushort_t* W2g = W2 + (size_t)g * 128 * 128;

    if (w == 0) {
        gemm_seg<192, 10>(acc, W0g, X0L, mi, quad);                       // Y0 cols 0..159
    } else if (w == 1) {
        gemm_seg<256, 8>(acc, W1g, X1L, mi, quad);                        // Y1 cols 0..127
    } else if (w == 2) {
        gemm_seg<256, 8>(acc, W1g + (size_t)128 * 256, X1L, mi, quad);    // Y1 cols 128..255
    } else {
        gemm_seg<192, 2>(acc, W0g + (size_t)160 * 192, X0L, mi, quad);    // Y0 cols 160..191
        gemm_seg<128, 8>(acc + 2, W2g, X2L, mi, quad);                    // Y2 cols 0..127
    }

    __syncthreads();   // everyone done reading X from LDS

    const float* B0g = B0 + g * 192;
    if (w == 0) {
        ywrite<192, 10, true>(acc, X0L, 0, B0g, mi, quad);
    } else if (w == 1) {
        ywrite<256, 8, false>(acc, X1L, 0, nullptr, mi, quad);
    } else if (w == 2) {
        ywrite<256, 8, false>(acc, X1L, 128, nullptr, mi, quad);
    } else {
        ywrite<192, 2, true>(acc, X0L, 160, B0g, mi, quad);
        ywrite<128, 8, false>(acc + 2, X2L, 0, nullptr, mi, quad);
    }
    __syncthreads();

    // ---- phase C: inverse rotate Y(LDS) -> out (8 rows/thread, fully unrolled) ----
    #pragma unroll
    for (int i = 0; i < 8; i++) {
        int nl = w * 8 + i;
        float sa = -TR[nl * 6 + 0], ca = TR[nl * 6 + 1];
        float sb = -TR[nl * 6 + 2], cb = TR[nl * 6 + 3];
        float sg = -TR[nl * 6 + 4], cg = TR[nl * 6 + 5];
        float s2a = 2.f * sa * ca, c2a = ca * ca - sa * sa;
        float s2b = 2.f * sb * cb, c2b = cb * cb - sb * sb;
        float s2g = 2.f * sg * cg, c2g = cg * cg - sg * sg;

        float* orow = out + (size_t)(base + nl) * 576;

        orow[c] = yread(X0L, nl, c, 192);

        float v0 = yread(X1L, nl, c, 256);
        float v1 = yread(X0L, nl, 64 + c, 192);
        float v2 = yread(X1L, nl, 128 + c, 256);
        zrot1(v0, v2, ca, sa);
        j1mul(J1, v0, v1, v2);
        zrot1(v0, v2, cb, sb);
        j1mul(J1, v0, v1, v2);
        zrot1(v0, v2, cg, sg);
        orow[64 + 3 * c]     = v0;
        orow[64 + 3 * c + 1] = v1;
        orow[64 + 3 * c + 2] = v2;

        float u0 = yread(X2L, nl, c, 128);
        float u1 = yread(X1L, nl, 64 + c, 256);
        float u2 = yread(X0L, nl, 128 + c, 192);
        float u3 = yread(X1L, nl, 192 + c, 256);
        float u4 = yread(X2L, nl, 64 + c, 128);
        zrot2(u0, u1, u3, u4, ca, sa, c2a, s2a);
        j2mul(J2, u0, u1, u2, u3, u4);
        zrot2(u0, u1, u3, u4, cb, sb, c2b, s2b);
        j2mul(J2, u0, u1, u2, u3, u4);
        zrot2(u0, u1, u3, u4, cg, sg, c2g, s2g);
        orow[256 + 5 * c]     = u0;
        orow[256 + 5 * c + 1] = u1;
        orow[256 + 5 * c + 2] = u2;
        orow[256 + 5 * c + 3] = u3;
        orow[256 + 5 * c + 4] = u4;
    }
}

extern "C" void kernel_launch(void* const* d_in, const int* in_sizes, int n_in,
                              void* d_out, int out_size, void* d_ws, size_t ws_size,
                              hipStream_t stream)
{
    const float* x      = (const float*)d_in[0];
    const float* alpha  = (const float*)d_in[1];
    const float* beta   = (const float*)d_in[2];
    const float* gamma_ = (const float*)d_in[3];
    const float* coef   = (const float*)d_in[4];
    const float* Jd1    = (const float*)d_in[5];
    const float* Jd2    = (const float*)d_in[6];
    const float* w_m0   = (const float*)d_in[7];
    const float* b_m0   = (const float*)d_in[8];
    const float* ws_m0  = (const float*)d_in[9];
    const float* bs_m0  = (const float*)d_in[10];
    const float* w_m1   = (const float*)d_in[11];
    const float* ws_m1  = (const float*)d_in[12];
    const float* w_m2   = (const float*)d_in[13];
    const float* ws_m2  = (const float*)d_in[14];

    char* wsb = (char*)d_ws;
    ushort_t* W0 = (ushort_t*)(wsb + BY_W0);
    ushort_t* W1 = (ushort_t*)(wsb + BY_W1);
    ushort_t* W2 = (ushort_t*)(wsb + BY_W2);
    float*    B0 = (float*)(wsb + BY_B0);
    float*    out = (float*)d_out;

    hipLaunchKernelGGL(mix_kernel, dim3(3718), dim3(256), 0, stream,
                       coef, w_m0, b_m0, ws_m0, bs_m0, w_m1, ws_m1, w_m2, ws_m2,
                       W0, B0, W1, W2);
    hipLaunchKernelGGL(fused_kernel, dim3(2000), dim3(256), 0, stream,
                       x, alpha, beta, gamma_, Jd1, Jd2, W0, W1, W2, B0, out);
}